// Round 11
// baseline (190.214 us; speedup 1.0000x reference)
//
#include <hip/hip_runtime.h>
#include <cstdint>
#include <cstddef>

// Linear attention: B=4 N=4096 C=768 H=12 d=64
// Pipeline: fused cast->bf16, GEMM1 128x128 BK=64 m97-style (proven),
// kv/ksum partials (32 chunks), widened reduce (kv->bf16), y via MFMA,
// GEMM2 128x128 BK=96 (A/B experiment: fewer barrier events vs occupancy).

typedef __attribute__((ext_vector_type(8))) short bf16x8;
typedef __attribute__((ext_vector_type(4))) float f32x4;

__device__ __forceinline__ unsigned short f2bf(float f) {
  uint32_t u = __builtin_bit_cast(uint32_t, f);
  u += 0x7FFFu + ((u >> 16) & 1u);  // RNE
  return (unsigned short)(u >> 16);
}
__device__ __forceinline__ float bf2f(unsigned short h) {
  uint32_t u = ((uint32_t)h) << 16;
  return __builtin_bit_cast(float, u);
}

__global__ __launch_bounds__(256) void cast3_kernel(
    const float* __restrict__ a, const float* __restrict__ b,
    const float* __restrict__ c, unsigned short* __restrict__ oa,
    unsigned short* __restrict__ ob, unsigned short* __restrict__ oc,
    int na4, int nb4, int nc4) {
  int i = blockIdx.x * 256 + threadIdx.x;
  const float* src;
  unsigned short* dst;
  if (i < na4) {
    src = a; dst = oa;
  } else if (i < na4 + nb4) {
    i -= na4; src = b; dst = ob;
  } else if (i < na4 + nb4 + nc4) {
    i -= na4 + nb4; src = c; dst = oc;
  } else {
    return;
  }
  float4 v = reinterpret_cast<const float4*>(src)[i];
  ushort4 o;
  o.x = f2bf(v.x); o.y = f2bf(v.y); o.z = f2bf(v.z); o.w = f2bf(v.w);
  reinterpret_cast<ushort4*>(dst)[i] = o;
}

#define GLOAD_LDS16(g, s)                                                     \
  __builtin_amdgcn_global_load_lds(                                           \
      (const __attribute__((address_space(1))) void*)(g),                     \
      (__attribute__((address_space(3))) void*)(s), 16, 0, 0)

__device__ __forceinline__ int xcd_swizzle(int lin, int nwg) {
  const int q = nwg >> 3, r = nwg & 7;
  const int xcd = lin & 7, idx = lin >> 3;
  return (xcd < r ? xcd * (q + 1) : r * (q + 1) + (xcd - r) * q) + idx;
}

// ============================================================================
// PROVEN: 128x128 tile, BK=64, 4 waves (2x2 of 64x64), 4x4 16x16x32 frags,
// global_load_lds width-16, plain __syncthreads (2/K-step), ~4 blocks/CU
// hides the barrier drain (m114). XOR chunk swizzle both-sides (rule #21),
// bijective XCD swizzle (m204). Schedule variants all slower (r2,3,5,7,8,10).
// ============================================================================
template <int PHI_COLS, bool OUT_BF16, bool BIAS>
__global__ __launch_bounds__(256) void gemm128(
    const unsigned short* __restrict__ A, const unsigned short* __restrict__ B,
    void* __restrict__ Cout, const float* __restrict__ bias, int M, int N, int K) {
  __shared__ unsigned short As[128 * 64];
  __shared__ unsigned short Bs[128 * 64];
  const int t = threadIdx.x;
  const int w = t >> 6;
  const int l = t & 63;
  const int r16 = l & 15;
  const int c4 = l >> 4;

  const int nx = gridDim.x;
  const int lin = xcd_swizzle(blockIdx.y * nx + blockIdx.x, gridDim.x * gridDim.y);
  const int m0 = (lin / nx) * 128;
  const int n0 = (lin % nx) * 128;

  const int srow = t >> 3;                      // 0..31
  const int schunk = (t & 7) ^ ((t >> 3) & 7);  // pre-swizzled source chunk
  const unsigned short* gA = A + (size_t)(m0 + srow) * K + schunk * 8;
  const unsigned short* gB = B + (size_t)(n0 + srow) * K + schunk * 8;
  const int lbase = w * 512;

  const int wm = (w >> 1) * 64;
  const int wn = (w & 1) * 64;

  f32x4 acc[4][4] = {};

  for (int k0 = 0; k0 < K; k0 += 64) {
#pragma unroll
    for (int i = 0; i < 4; ++i) {
      GLOAD_LDS16(gA + k0 + (size_t)i * 32 * K, &As[lbase + i * 2048]);
      GLOAD_LDS16(gB + k0 + (size_t)i * 32 * K, &Bs[lbase + i * 2048]);
    }
    __syncthreads();
#pragma unroll
    for (int kk = 0; kk < 2; ++kk) {
      bf16x8 af[4], bfr[4];
#pragma unroll
      for (int mi = 0; mi < 4; ++mi) {
        const int R = wm + mi * 16 + r16;
        const int ch = (kk * 4 + c4) ^ (R & 7);
        af[mi] = *reinterpret_cast<const bf16x8*>(&As[R * 64 + ch * 8]);
      }
#pragma unroll
      for (int ni = 0; ni < 4; ++ni) {
        const int R = wn + ni * 16 + r16;
        const int ch = (kk * 4 + c4) ^ (R & 7);
        bfr[ni] = *reinterpret_cast<const bf16x8*>(&Bs[R * 64 + ch * 8]);
      }
#pragma unroll
      for (int mi = 0; mi < 4; ++mi)
#pragma unroll
        for (int ni = 0; ni < 4; ++ni)
          acc[mi][ni] = __builtin_amdgcn_mfma_f32_16x16x32_bf16(af[mi], bfr[ni], acc[mi][ni], 0, 0, 0);
    }
    __syncthreads();
  }

  const int rbase = c4 * 4;
#pragma unroll
  for (int mi = 0; mi < 4; ++mi) {
    const int row = m0 + wm + mi * 16 + rbase;
#pragma unroll
    for (int ni = 0; ni < 4; ++ni) {
      const int col = n0 + wn + ni * 16 + r16;
      float bv = 0.0f;
      if constexpr (BIAS) bv = bias[col];
      f32x4 v = acc[mi][ni];
#pragma unroll
      for (int r = 0; r < 4; ++r) {
        float x = v[r] + bv;
        if constexpr (PHI_COLS > 0) {
          if (col < PHI_COLS) x = (x > 0.0f) ? (x + 1.0f) : __expf(x);  // elu+1
        }
        if constexpr (OUT_BF16)
          ((unsigned short*)Cout)[(size_t)(row + r) * N + col] = f2bf(x);
        else
          ((float*)Cout)[(size_t)(row + r) * N + col] = x;
      }
    }
  }
}

// ============================================================================
// EXPERIMENT (GEMM2 only): BK=96 = 3 slabs of [128][32] (round-7/8 verified
// conflict-free slab swizzle). K-steps 12->8 (-33% barrier events); LDS 48KB
// -> 3 blocks/CU (vs 4). Tests whether drain-count or TLP dominates.
// Requires K % 96 == 0.
// ============================================================================
template <int PHI_COLS, bool OUT_BF16, bool BIAS>
__global__ __launch_bounds__(256) void gemm128_bk96(
    const unsigned short* __restrict__ A, const unsigned short* __restrict__ B,
    void* __restrict__ Cout, const float* __restrict__ bias, int M, int N, int K) {
  __shared__ unsigned short As[3 * 128 * 32];  // slab kk at kk*4096
  __shared__ unsigned short Bs[3 * 128 * 32];
  const int t = threadIdx.x;
  const int w = t >> 6;
  const int l = t & 63;
  const int r16 = l & 15;
  const int c4 = l >> 4;

  const int nx = gridDim.x;
  const int lin = xcd_swizzle(blockIdx.y * nx + blockIdx.x, gridDim.x * gridDim.y);
  const int m0 = (lin / nx) * 128;
  const int n0 = (lin % nx) * 128;

  // staging per slab-half: row = i*64 + (t>>2), chunk t&3; source chunk
  // pre-swizzled by (row>>1)&3 = (t>>3)&3 (round-7 verified scheme).
  const int srow = t >> 2;                     // 0..63
  const int csrc = (t & 3) ^ ((t >> 3) & 3);
  const unsigned short* gA = A + (size_t)(m0 + srow) * K + csrc * 8;
  const unsigned short* gB = B + (size_t)(n0 + srow) * K + csrc * 8;
  const int lb = w * 512;

  const int wm = (w >> 1) * 64;
  const int wn = (w & 1) * 64;
  const int rch = (c4 ^ ((r16 >> 1) & 3)) * 8;  // read-side swizzled chunk

  f32x4 acc[4][4] = {};

  for (int k0 = 0; k0 < K; k0 += 96) {
#pragma unroll
    for (int kk = 0; kk < 3; ++kk) {
      const int kc = k0 + kk * 32;
      GLOAD_LDS16(gA + kc, &As[kk * 4096 + lb]);
      GLOAD_LDS16(gA + kc + (size_t)64 * K, &As[kk * 4096 + 2048 + lb]);
      GLOAD_LDS16(gB + kc, &Bs[kk * 4096 + lb]);
      GLOAD_LDS16(gB + kc + (size_t)64 * K, &Bs[kk * 4096 + 2048 + lb]);
    }
    __syncthreads();
#pragma unroll
    for (int kk = 0; kk < 3; ++kk) {
      bf16x8 af[4], bq[4];
#pragma unroll
      for (int mi = 0; mi < 4; ++mi)
        af[mi] = *reinterpret_cast<const bf16x8*>(
            &As[kk * 4096 + (wm + mi * 16 + r16) * 32 + rch]);
#pragma unroll
      for (int ni = 0; ni < 4; ++ni)
        bq[ni] = *reinterpret_cast<const bf16x8*>(
            &Bs[kk * 4096 + (wn + ni * 16 + r16) * 32 + rch]);
#pragma unroll
      for (int mi = 0; mi < 4; ++mi)
#pragma unroll
        for (int ni = 0; ni < 4; ++ni)
          acc[mi][ni] = __builtin_amdgcn_mfma_f32_16x16x32_bf16(af[mi], bq[ni], acc[mi][ni], 0, 0, 0);
    }
    __syncthreads();
  }

  const int rbase = c4 * 4;
#pragma unroll
  for (int mi = 0; mi < 4; ++mi) {
    const int row = m0 + wm + mi * 16 + rbase;
#pragma unroll
    for (int ni = 0; ni < 4; ++ni) {
      const int col = n0 + wn + ni * 16 + r16;
      float bv = 0.0f;
      if constexpr (BIAS) bv = bias[col];
      f32x4 v = acc[mi][ni];
#pragma unroll
      for (int r = 0; r < 4; ++r) {
        float x = v[r] + bv;
        if constexpr (PHI_COLS > 0) {
          if (col < PHI_COLS) x = (x > 0.0f) ? (x + 1.0f) : __expf(x);
        }
        if constexpr (OUT_BF16)
          ((unsigned short*)Cout)[(size_t)(row + r) * N + col] = f2bf(x);
        else
          ((float*)Cout)[(size_t)(row + r) * N + col] = x;
      }
    }
  }
}

// kv[m,d] partials over 128-n chunks, 32 chunks per (b,h).
__global__ __launch_bounds__(256) void kv_partial_kernel(
    const unsigned short* __restrict__ qkv, float* __restrict__ kv_part,
    float* __restrict__ ksum_part) {
  const int bh = blockIdx.x;
  const int chunk = blockIdx.y;
  const int b = bh / 12, h = bh % 12;
  const int t = threadIdx.x;
  const int tm = (t >> 4) * 4;
  const int td = (t & 15) * 4;
  const unsigned short* base = qkv + ((size_t)(b * 4096 + chunk * 128)) * 2304;
  const unsigned short* kptr = base + 768 + h * 64 + td;
  const unsigned short* vptr = base + 1536 + h * 64 + tm;
  float acc[4][4] = {};
  float ks[4] = {};
#pragma unroll 8
  for (int n = 0; n < 128; ++n) {
    const size_t off = (size_t)n * 2304;
    ushort4 ku = *reinterpret_cast<const ushort4*>(kptr + off);
    ushort4 vu = *reinterpret_cast<const ushort4*>(vptr + off);
    float kf[4] = {bf2f(ku.x), bf2f(ku.y), bf2f(ku.z), bf2f(ku.w)};
    float vf[4] = {bf2f(vu.x), bf2f(vu.y), bf2f(vu.z), bf2f(vu.w)};
#pragma unroll
    for (int i = 0; i < 4; ++i)
#pragma unroll
      for (int j = 0; j < 4; ++j) acc[i][j] += vf[i] * kf[j];
#pragma unroll
    for (int j = 0; j < 4; ++j) ks[j] += kf[j];
  }
  float* kvp = kv_part + ((size_t)(bh * 32 + chunk)) * 4096;
#pragma unroll
  for (int i = 0; i < 4; ++i)
#pragma unroll
    for (int j = 0; j < 4; ++j) kvp[(tm + i) * 64 + td + j] = acc[i][j];
  if (tm == 0) {
    float* ksp = ksum_part + (size_t)(bh * 32 + chunk) * 64;
#pragma unroll
    for (int j = 0; j < 4; ++j) ksp[td + j] = ks[j];
  }
}

__global__ __launch_bounds__(256) void kv_reduce_kernel(
    const float* __restrict__ kv_part, const float* __restrict__ ksum_part,
    unsigned short* __restrict__ kvb, float* __restrict__ ksum) {
  const int bh = blockIdx.x;
  const int seg = blockIdx.y;
  const int t = threadIdx.x;
  const int e = seg * 1024 + t * 4;
  float4 s = {0.f, 0.f, 0.f, 0.f};
#pragma unroll
  for (int c = 0; c < 32; ++c) {
    float4 v = *reinterpret_cast<const float4*>(
        &kv_part[((size_t)(bh * 32 + c)) * 4096 + e]);
    s.x += v.x; s.y += v.y; s.z += v.z; s.w += v.w;
  }
  ushort4 o;
  o.x = f2bf(s.x); o.y = f2bf(s.y); o.z = f2bf(s.z); o.w = f2bf(s.w);
  *reinterpret_cast<ushort4*>(&kvb[(size_t)bh * 4096 + e]) = o;
  if (seg == 0 && t < 64) {
    float ss = 0.f;
#pragma unroll
    for (int c = 0; c < 32; ++c) ss += ksum_part[(size_t)(bh * 32 + c) * 64 + t];
    ksum[bh * 64 + t] = ss;
  }
}

// y[n,m] = z[n] * sum_d q[n,d] kv[m,d], z[n]=1/(q[n,:].ksum+eps), via MFMA.
__global__ __launch_bounds__(256) void y_mfma_kernel(
    const unsigned short* __restrict__ qkv, const unsigned short* __restrict__ kvb,
    const float* __restrict__ ksum, unsigned short* __restrict__ ybf) {
  __shared__ unsigned short Qs[128 * 64];
  __shared__ unsigned short KVs[64 * 64];
  __shared__ float zs[128];
  const int bh = blockIdx.x;
  const int n0 = blockIdx.y * 128;
  const int b = bh / 12, h = bh % 12;
  const int t = threadIdx.x;
  const int w = t >> 6;
  const int l = t & 63;
  const int r16 = l & 15;
  const int c4 = l >> 4;

  const int srow = t >> 3;
  const int schunk = (t & 7) ^ ((t >> 3) & 7);
  const unsigned short* gQ =
      qkv + ((size_t)(b * 4096 + n0 + srow)) * 2304 + h * 64 + schunk * 8;
  const unsigned short* gKV = kvb + (size_t)bh * 4096 + srow * 64 + schunk * 8;
  const int lbase = w * 512;
#pragma unroll
  for (int i = 0; i < 4; ++i)
    GLOAD_LDS16(gQ + (size_t)i * 32 * 2304, &Qs[lbase + i * 2048]);
#pragma unroll
  for (int i = 0; i < 2; ++i)
    GLOAD_LDS16(gKV + i * 32 * 64, &KVs[lbase + i * 2048]);
  __syncthreads();

  const int wr = w * 32;
  f32x4 acc[2][4] = {};
#pragma unroll
  for (int kk = 0; kk < 2; ++kk) {
    bf16x8 af[2], bfr[4];
#pragma unroll
    for (int mi = 0; mi < 2; ++mi) {
      const int R = wr + mi * 16 + r16;
      const int ch = (kk * 4 + c4) ^ (R & 7);
      af[mi] = *reinterpret_cast<const bf16x8*>(&Qs[R * 64 + ch * 8]);
    }
#pragma unroll
    for (int ni = 0; ni < 4; ++ni) {
      const int R = ni * 16 + r16;
      const int ch = (kk * 4 + c4) ^ (R & 7);
      bfr[ni] = *reinterpret_cast<const bf16x8*>(&KVs[R * 64 + ch * 8]);
    }
#pragma unroll
    for (int mi = 0; mi < 2; ++mi)
#pragma unroll
      for (int ni = 0; ni < 4; ++ni)
        acc[mi][ni] = __builtin_amdgcn_mfma_f32_16x16x32_bf16(af[mi], bfr[ni], acc[mi][ni], 0, 0, 0);
  }

  if (t < 128) {
    const float* ks = ksum + bh * 64;
    float s = 0.f;
#pragma unroll
    for (int c = 0; c < 8; ++c) {
      bf16x8 qv = *reinterpret_cast<const bf16x8*>(&Qs[t * 64 + ((c ^ (t & 7)) * 8)]);
#pragma unroll
      for (int j = 0; j < 8; ++j) s += bf2f((unsigned short)qv[j]) * ks[c * 8 + j];
    }
    zs[t] = 1.0f / (s + 1e-6f);
  }
  __syncthreads();

  unsigned short* ybase = ybf + ((size_t)(b * 4096 + n0)) * 768 + h * 64;
#pragma unroll
  for (int mi = 0; mi < 2; ++mi) {
#pragma unroll
    for (int ni = 0; ni < 4; ++ni) {
      const int col = ni * 16 + r16;
      f32x4 v = acc[mi][ni];
#pragma unroll
      for (int r = 0; r < 4; ++r) {
        const int row = wr + mi * 16 + c4 * 4 + r;
        ybase[(size_t)row * 768 + col] = f2bf(v[r] * zs[row]);
      }
    }
  }
}

extern "C" void kernel_launch(void* const* d_in, const int* in_sizes, int n_in,
                              void* d_out, int out_size, void* d_ws, size_t ws_size,
                              hipStream_t stream) {
  const float* x = (const float*)d_in[0];
  const float* Wqkv = (const float*)d_in[1];
  const float* Wproj = (const float*)d_in[2];
  const float* bproj = (const float*)d_in[3];
  float* out = (float*)d_out;

  const int M = 16384;
  const int C = 768;
  const int N1 = 2304;

  char* ws = (char*)d_ws;
  size_t off = 0;
  unsigned short* xb = (unsigned short*)(ws + off);  off += (size_t)M * C * 2;
  unsigned short* wqb = (unsigned short*)(ws + off); off += (size_t)N1 * C * 2;
  unsigned short* wpb = (unsigned short*)(ws + off); off += (size_t)C * C * 2;
  unsigned short* qkvb = (unsigned short*)(ws + off); off += (size_t)M * N1 * 2;
  unsigned short* kvb = (unsigned short*)(ws + off); off += (size_t)48 * 4096 * 2;
  float* ksum = (float*)(ws + off);      off += (size_t)48 * 64 * 4;
  unsigned short* yb = (unsigned short*)(ws + off); off += (size_t)M * C * 2;
  float* ksum_part = (float*)(ws + off); off += (size_t)48 * 32 * 64 * 4;
  float* kv_part = (float*)xb;  // overlays xb (dead after GEMM1)

  const int na4 = M * C / 4, nb4 = N1 * C / 4, nc4 = C * C / 4;
  cast3_kernel<<<(na4 + nb4 + nc4 + 255) / 256, 256, 0, stream>>>(
      x, Wqkv, Wproj, xb, wqb, wpb, na4, nb4, nc4);

  // qkv = x @ Wqkv^T, phi fused on q,k columns, bf16 out — PROVEN BK=64
  gemm128<1536, true, false>
      <<<dim3(N1 / 128, M / 128), 256, 0, stream>>>(xb, wqb, qkvb, nullptr, M, N1, C);

  kv_partial_kernel<<<dim3(48, 32), 256, 0, stream>>>(qkvb, kv_part, ksum_part);
  kv_reduce_kernel<<<dim3(48, 4), 256, 0, stream>>>(kv_part, ksum_part, kvb, ksum);
  y_mfma_kernel<<<dim3(48, 32), 256, 0, stream>>>(qkvb, kvb, ksum, yb);

  // out = y @ Wproj^T + b, fp32 out — BK=96 EXPERIMENT
  gemm128_bk96<0, false, true>
      <<<dim3(C / 128, M / 128), 256, 0, stream>>>(yb, wpb, out, bproj, M, C, C);
}

// Round 12
// 181.890 us; speedup vs baseline: 1.0458x; 1.0458x over previous
//
#include <hip/hip_runtime.h>
#include <cstdint>
#include <cstddef>

// Linear attention: B=4 N=4096 C=768 H=12 d=64
// Pipeline: fused cast->bf16, GEMM1 128x128 BK=64 m97-style (x@Wqkv^T, fused
// phi), kv/ksum partials (32 chunks), widened reduce (kv->bf16), y via MFMA,
// GEMM2 128x128 BK=64 (y@Wproj^T + bias, fp32 out).
//
// Schedule ledger (this session, GEMM1 unless noted): BK=64 2-barrier = 92us
// BEATS 8-phase(118), 1-region ring(114), cross-buffer dbuf(103), BK=32(108),
// kk-split 8-phase(113), BK=96(GEMM2 +8us). Keep the 2-barrier loop.

typedef __attribute__((ext_vector_type(8))) short bf16x8;
typedef __attribute__((ext_vector_type(4))) float f32x4;

__device__ __forceinline__ unsigned short f2bf(float f) {
  uint32_t u = __builtin_bit_cast(uint32_t, f);
  u += 0x7FFFu + ((u >> 16) & 1u);  // RNE
  return (unsigned short)(u >> 16);
}
__device__ __forceinline__ float bf2f(unsigned short h) {
  uint32_t u = ((uint32_t)h) << 16;
  return __builtin_bit_cast(float, u);
}

__global__ __launch_bounds__(256) void cast3_kernel(
    const float* __restrict__ a, const float* __restrict__ b,
    const float* __restrict__ c, unsigned short* __restrict__ oa,
    unsigned short* __restrict__ ob, unsigned short* __restrict__ oc,
    int na4, int nb4, int nc4) {
  int i = blockIdx.x * 256 + threadIdx.x;
  const float* src;
  unsigned short* dst;
  if (i < na4) {
    src = a; dst = oa;
  } else if (i < na4 + nb4) {
    i -= na4; src = b; dst = ob;
  } else if (i < na4 + nb4 + nc4) {
    i -= na4 + nb4; src = c; dst = oc;
  } else {
    return;
  }
  float4 v = reinterpret_cast<const float4*>(src)[i];
  ushort4 o;
  o.x = f2bf(v.x); o.y = f2bf(v.y); o.z = f2bf(v.z); o.w = f2bf(v.w);
  reinterpret_cast<ushort4*>(dst)[i] = o;
}

#define GLOAD_LDS16(g, s)                                                     \
  __builtin_amdgcn_global_load_lds(                                           \
      (const __attribute__((address_space(1))) void*)(g),                     \
      (__attribute__((address_space(3))) void*)(s), 16, 0, 0)

__device__ __forceinline__ int xcd_swizzle(int lin, int nwg) {
  const int q = nwg >> 3, r = nwg & 7;
  const int xcd = lin & 7, idx = lin >> 3;
  return (xcd < r ? xcd * (q + 1) : r * (q + 1) + (xcd - r) * q) + idx;
}

// ============================================================================
// PROVEN: 128x128 tile, BK=64, 4 waves (2x2 of 64x64), 4x4 16x16x32 frags,
// global_load_lds width-16, plain __syncthreads (2/K-step), multi-block
// co-residency hides the barrier drain (m114). XOR chunk swizzle both-sides
// (rule #21), bijective XCD swizzle (m204).
// ============================================================================
template <int PHI_COLS, bool OUT_BF16, bool BIAS>
__global__ __launch_bounds__(256) void gemm128(
    const unsigned short* __restrict__ A, const unsigned short* __restrict__ B,
    void* __restrict__ Cout, const float* __restrict__ bias, int M, int N, int K) {
  __shared__ unsigned short As[128 * 64];
  __shared__ unsigned short Bs[128 * 64];
  const int t = threadIdx.x;
  const int w = t >> 6;
  const int l = t & 63;
  const int r16 = l & 15;
  const int c4 = l >> 4;

  const int nx = gridDim.x;
  const int lin = xcd_swizzle(blockIdx.y * nx + blockIdx.x, gridDim.x * gridDim.y);
  const int m0 = (lin / nx) * 128;
  const int n0 = (lin % nx) * 128;

  const int srow = t >> 3;                      // 0..31
  const int schunk = (t & 7) ^ ((t >> 3) & 7);  // pre-swizzled source chunk
  const unsigned short* gA = A + (size_t)(m0 + srow) * K + schunk * 8;
  const unsigned short* gB = B + (size_t)(n0 + srow) * K + schunk * 8;
  const int lbase = w * 512;

  const int wm = (w >> 1) * 64;
  const int wn = (w & 1) * 64;

  f32x4 acc[4][4] = {};

  for (int k0 = 0; k0 < K; k0 += 64) {
#pragma unroll
    for (int i = 0; i < 4; ++i) {
      GLOAD_LDS16(gA + k0 + (size_t)i * 32 * K, &As[lbase + i * 2048]);
      GLOAD_LDS16(gB + k0 + (size_t)i * 32 * K, &Bs[lbase + i * 2048]);
    }
    __syncthreads();
#pragma unroll
    for (int kk = 0; kk < 2; ++kk) {
      bf16x8 af[4], bfr[4];
#pragma unroll
      for (int mi = 0; mi < 4; ++mi) {
        const int R = wm + mi * 16 + r16;
        const int ch = (kk * 4 + c4) ^ (R & 7);
        af[mi] = *reinterpret_cast<const bf16x8*>(&As[R * 64 + ch * 8]);
      }
#pragma unroll
      for (int ni = 0; ni < 4; ++ni) {
        const int R = wn + ni * 16 + r16;
        const int ch = (kk * 4 + c4) ^ (R & 7);
        bfr[ni] = *reinterpret_cast<const bf16x8*>(&Bs[R * 64 + ch * 8]);
      }
#pragma unroll
      for (int mi = 0; mi < 4; ++mi)
#pragma unroll
        for (int ni = 0; ni < 4; ++ni)
          acc[mi][ni] = __builtin_amdgcn_mfma_f32_16x16x32_bf16(af[mi], bfr[ni], acc[mi][ni], 0, 0, 0);
    }
    __syncthreads();
  }

  // epilogue: C/D layout col=lane&15, row=(lane>>4)*4+reg (m89/m91 verified)
  const int rbase = c4 * 4;
#pragma unroll
  for (int mi = 0; mi < 4; ++mi) {
    const int row = m0 + wm + mi * 16 + rbase;
#pragma unroll
    for (int ni = 0; ni < 4; ++ni) {
      const int col = n0 + wn + ni * 16 + r16;
      float bv = 0.0f;
      if constexpr (BIAS) bv = bias[col];
      f32x4 v = acc[mi][ni];
#pragma unroll
      for (int r = 0; r < 4; ++r) {
        float x = v[r] + bv;
        if constexpr (PHI_COLS > 0) {
          if (col < PHI_COLS) x = (x > 0.0f) ? (x + 1.0f) : __expf(x);  // elu+1
        }
        if constexpr (OUT_BF16)
          ((unsigned short*)Cout)[(size_t)(row + r) * N + col] = f2bf(x);
        else
          ((float*)Cout)[(size_t)(row + r) * N + col] = x;
      }
    }
  }
}

// kv[m,d] partials over 128-n chunks, 32 chunks per (b,h).
__global__ __launch_bounds__(256) void kv_partial_kernel(
    const unsigned short* __restrict__ qkv, float* __restrict__ kv_part,
    float* __restrict__ ksum_part) {
  const int bh = blockIdx.x;
  const int chunk = blockIdx.y;
  const int b = bh / 12, h = bh % 12;
  const int t = threadIdx.x;
  const int tm = (t >> 4) * 4;
  const int td = (t & 15) * 4;
  const unsigned short* base = qkv + ((size_t)(b * 4096 + chunk * 128)) * 2304;
  const unsigned short* kptr = base + 768 + h * 64 + td;
  const unsigned short* vptr = base + 1536 + h * 64 + tm;
  float acc[4][4] = {};
  float ks[4] = {};
#pragma unroll 8
  for (int n = 0; n < 128; ++n) {
    const size_t off = (size_t)n * 2304;
    ushort4 ku = *reinterpret_cast<const ushort4*>(kptr + off);
    ushort4 vu = *reinterpret_cast<const ushort4*>(vptr + off);
    float kf[4] = {bf2f(ku.x), bf2f(ku.y), bf2f(ku.z), bf2f(ku.w)};
    float vf[4] = {bf2f(vu.x), bf2f(vu.y), bf2f(vu.z), bf2f(vu.w)};
#pragma unroll
    for (int i = 0; i < 4; ++i)
#pragma unroll
      for (int j = 0; j < 4; ++j) acc[i][j] += vf[i] * kf[j];
#pragma unroll
    for (int j = 0; j < 4; ++j) ks[j] += kf[j];
  }
  float* kvp = kv_part + ((size_t)(bh * 32 + chunk)) * 4096;
#pragma unroll
  for (int i = 0; i < 4; ++i)
#pragma unroll
    for (int j = 0; j < 4; ++j) kvp[(tm + i) * 64 + td + j] = acc[i][j];
  if (tm == 0) {
    float* ksp = ksum_part + (size_t)(bh * 32 + chunk) * 64;
#pragma unroll
    for (int j = 0; j < 4; ++j) ksp[td + j] = ks[j];
  }
}

// widened reduce: grid (48,4); float4 loads; kv emitted bf16, ksum f32.
__global__ __launch_bounds__(256) void kv_reduce_kernel(
    const float* __restrict__ kv_part, const float* __restrict__ ksum_part,
    unsigned short* __restrict__ kvb, float* __restrict__ ksum) {
  const int bh = blockIdx.x;
  const int seg = blockIdx.y;
  const int t = threadIdx.x;
  const int e = seg * 1024 + t * 4;
  float4 s = {0.f, 0.f, 0.f, 0.f};
#pragma unroll
  for (int c = 0; c < 32; ++c) {
    float4 v = *reinterpret_cast<const float4*>(
        &kv_part[((size_t)(bh * 32 + c)) * 4096 + e]);
    s.x += v.x; s.y += v.y; s.z += v.z; s.w += v.w;
  }
  ushort4 o;
  o.x = f2bf(s.x); o.y = f2bf(s.y); o.z = f2bf(s.z); o.w = f2bf(s.w);
  *reinterpret_cast<ushort4*>(&kvb[(size_t)bh * 4096 + e]) = o;
  if (seg == 0 && t < 64) {
    float ss = 0.f;
#pragma unroll
    for (int c = 0; c < 32; ++c) ss += ksum_part[(size_t)(bh * 32 + c) * 64 + t];
    ksum[bh * 64 + t] = ss;
  }
}

// y[n,m] = z[n] * sum_d q[n,d] kv[m,d], z[n]=1/(q[n,:].ksum+eps), via MFMA.
__global__ __launch_bounds__(256) void y_mfma_kernel(
    const unsigned short* __restrict__ qkv, const unsigned short* __restrict__ kvb,
    const float* __restrict__ ksum, unsigned short* __restrict__ ybf) {
  __shared__ unsigned short Qs[128 * 64];
  __shared__ unsigned short KVs[64 * 64];
  __shared__ float zs[128];
  const int bh = blockIdx.x;
  const int n0 = blockIdx.y * 128;
  const int b = bh / 12, h = bh % 12;
  const int t = threadIdx.x;
  const int w = t >> 6;
  const int l = t & 63;
  const int r16 = l & 15;
  const int c4 = l >> 4;

  const int srow = t >> 3;
  const int schunk = (t & 7) ^ ((t >> 3) & 7);
  const unsigned short* gQ =
      qkv + ((size_t)(b * 4096 + n0 + srow)) * 2304 + h * 64 + schunk * 8;
  const unsigned short* gKV = kvb + (size_t)bh * 4096 + srow * 64 + schunk * 8;
  const int lbase = w * 512;
#pragma unroll
  for (int i = 0; i < 4; ++i)
    GLOAD_LDS16(gQ + (size_t)i * 32 * 2304, &Qs[lbase + i * 2048]);
#pragma unroll
  for (int i = 0; i < 2; ++i)
    GLOAD_LDS16(gKV + i * 32 * 64, &KVs[lbase + i * 2048]);
  __syncthreads();

  const int wr = w * 32;
  f32x4 acc[2][4] = {};
#pragma unroll
  for (int kk = 0; kk < 2; ++kk) {
    bf16x8 af[2], bfr[4];
#pragma unroll
    for (int mi = 0; mi < 2; ++mi) {
      const int R = wr + mi * 16 + r16;
      const int ch = (kk * 4 + c4) ^ (R & 7);
      af[mi] = *reinterpret_cast<const bf16x8*>(&Qs[R * 64 + ch * 8]);
    }
#pragma unroll
    for (int ni = 0; ni < 4; ++ni) {
      const int R = ni * 16 + r16;
      const int ch = (kk * 4 + c4) ^ (R & 7);
      bfr[ni] = *reinterpret_cast<const bf16x8*>(&KVs[R * 64 + ch * 8]);
    }
#pragma unroll
    for (int mi = 0; mi < 2; ++mi)
#pragma unroll
      for (int ni = 0; ni < 4; ++ni)
        acc[mi][ni] = __builtin_amdgcn_mfma_f32_16x16x32_bf16(af[mi], bfr[ni], acc[mi][ni], 0, 0, 0);
  }

  if (t < 128) {
    const float* ks = ksum + bh * 64;
    float s = 0.f;
#pragma unroll
    for (int c = 0; c < 8; ++c) {
      bf16x8 qv = *reinterpret_cast<const bf16x8*>(&Qs[t * 64 + ((c ^ (t & 7)) * 8)]);
#pragma unroll
      for (int j = 0; j < 8; ++j) s += bf2f((unsigned short)qv[j]) * ks[c * 8 + j];
    }
    zs[t] = 1.0f / (s + 1e-6f);
  }
  __syncthreads();

  unsigned short* ybase = ybf + ((size_t)(b * 4096 + n0)) * 768 + h * 64;
#pragma unroll
  for (int mi = 0; mi < 2; ++mi) {
#pragma unroll
    for (int ni = 0; ni < 4; ++ni) {
      const int col = ni * 16 + r16;
      f32x4 v = acc[mi][ni];
#pragma unroll
      for (int r = 0; r < 4; ++r) {
        const int row = wr + mi * 16 + c4 * 4 + r;
        ybase[(size_t)row * 768 + col] = f2bf(v[r] * zs[row]);
      }
    }
  }
}

extern "C" void kernel_launch(void* const* d_in, const int* in_sizes, int n_in,
                              void* d_out, int out_size, void* d_ws, size_t ws_size,
                              hipStream_t stream) {
  const float* x = (const float*)d_in[0];
  const float* Wqkv = (const float*)d_in[1];
  const float* Wproj = (const float*)d_in[2];
  const float* bproj = (const float*)d_in[3];
  float* out = (float*)d_out;

  const int M = 16384;
  const int C = 768;
  const int N1 = 2304;

  char* ws = (char*)d_ws;
  size_t off = 0;
  unsigned short* xb = (unsigned short*)(ws + off);  off += (size_t)M * C * 2;
  unsigned short* wqb = (unsigned short*)(ws + off); off += (size_t)N1 * C * 2;
  unsigned short* wpb = (unsigned short*)(ws + off); off += (size_t)C * C * 2;
  unsigned short* qkvb = (unsigned short*)(ws + off); off += (size_t)M * N1 * 2;
  unsigned short* kvb = (unsigned short*)(ws + off); off += (size_t)48 * 4096 * 2;
  float* ksum = (float*)(ws + off);      off += (size_t)48 * 64 * 4;
  unsigned short* yb = (unsigned short*)(ws + off); off += (size_t)M * C * 2;
  float* ksum_part = (float*)(ws + off); off += (size_t)48 * 32 * 64 * 4;
  float* kv_part = (float*)xb;  // overlays xb (dead after GEMM1)

  const int na4 = M * C / 4, nb4 = N1 * C / 4, nc4 = C * C / 4;
  cast3_kernel<<<(na4 + nb4 + nc4 + 255) / 256, 256, 0, stream>>>(
      x, Wqkv, Wproj, xb, wqb, wpb, na4, nb4, nc4);

  // qkv = x @ Wqkv^T, phi fused on q,k columns, bf16 out
  gemm128<1536, true, false>
      <<<dim3(N1 / 128, M / 128), 256, 0, stream>>>(xb, wqb, qkvb, nullptr, M, N1, C);

  kv_partial_kernel<<<dim3(48, 32), 256, 0, stream>>>(qkvb, kv_part, ksum_part);
  kv_reduce_kernel<<<dim3(48, 4), 256, 0, stream>>>(kv_part, ksum_part, kvb, ksum);
  y_mfma_kernel<<<dim3(48, 32), 256, 0, stream>>>(qkvb, kvb, ksum, yb);

  // out = y @ Wproj^T + b, fp32 out
  gemm128<0, false, true>
      <<<dim3(C / 128, M / 128), 256, 0, stream>>>(yb, wpb, out, bproj, M, C, C);
}

// Round 13
// 156.580 us; speedup vs baseline: 1.2148x; 1.1616x over previous
//
#include <hip/hip_runtime.h>
#include <cstdint>
#include <cstddef>

// Linear attention: B=4 N=4096 C=768 H=12 d=64
// Pipeline: fused cast->bf16, GEMM1 128x128 BK=64 m97-style (x@Wqkv^T, fused
// phi), kv/ksum partials (16 chunks, LDS-f32-staged), widened reduce
// (kv->bf16), y via MFMA, GEMM2 128x128 BK=64 (y@Wproj^T + bias, fp32 out).
//
// Schedule ledger (GEMM1 unless noted): BK=64 2-barrier = 92us BEATS
// 8-phase(118), 1-region ring(114), cross-buffer dbuf(103), BK=32(108),
// kk-split 8-phase(113), BK=96(GEMM2 +8us). Keep the 2-barrier loop.

typedef __attribute__((ext_vector_type(8))) short bf16x8;
typedef __attribute__((ext_vector_type(4))) float f32x4;

__device__ __forceinline__ unsigned short f2bf(float f) {
  uint32_t u = __builtin_bit_cast(uint32_t, f);
  u += 0x7FFFu + ((u >> 16) & 1u);  // RNE
  return (unsigned short)(u >> 16);
}
__device__ __forceinline__ float bf2f(unsigned short h) {
  uint32_t u = ((uint32_t)h) << 16;
  return __builtin_bit_cast(float, u);
}

__global__ __launch_bounds__(256) void cast3_kernel(
    const float* __restrict__ a, const float* __restrict__ b,
    const float* __restrict__ c, unsigned short* __restrict__ oa,
    unsigned short* __restrict__ ob, unsigned short* __restrict__ oc,
    int na4, int nb4, int nc4) {
  int i = blockIdx.x * 256 + threadIdx.x;
  const float* src;
  unsigned short* dst;
  if (i < na4) {
    src = a; dst = oa;
  } else if (i < na4 + nb4) {
    i -= na4; src = b; dst = ob;
  } else if (i < na4 + nb4 + nc4) {
    i -= na4 + nb4; src = c; dst = oc;
  } else {
    return;
  }
  float4 v = reinterpret_cast<const float4*>(src)[i];
  ushort4 o;
  o.x = f2bf(v.x); o.y = f2bf(v.y); o.z = f2bf(v.z); o.w = f2bf(v.w);
  reinterpret_cast<ushort4*>(dst)[i] = o;
}

#define GLOAD_LDS16(g, s)                                                     \
  __builtin_amdgcn_global_load_lds(                                           \
      (const __attribute__((address_space(1))) void*)(g),                     \
      (__attribute__((address_space(3))) void*)(s), 16, 0, 0)

__device__ __forceinline__ int xcd_swizzle(int lin, int nwg) {
  const int q = nwg >> 3, r = nwg & 7;
  const int xcd = lin & 7, idx = lin >> 3;
  return (xcd < r ? xcd * (q + 1) : r * (q + 1) + (xcd - r) * q) + idx;
}

// ============================================================================
// PROVEN: 128x128 tile, BK=64, 4 waves (2x2 of 64x64), 4x4 16x16x32 frags,
// global_load_lds width-16, plain __syncthreads (2/K-step), multi-block
// co-residency hides the barrier drain (m114). XOR chunk swizzle both-sides
// (rule #21), bijective XCD swizzle (m204).
// ============================================================================
template <int PHI_COLS, bool OUT_BF16, bool BIAS>
__global__ __launch_bounds__(256) void gemm128(
    const unsigned short* __restrict__ A, const unsigned short* __restrict__ B,
    void* __restrict__ Cout, const float* __restrict__ bias, int M, int N, int K) {
  __shared__ unsigned short As[128 * 64];
  __shared__ unsigned short Bs[128 * 64];
  const int t = threadIdx.x;
  const int w = t >> 6;
  const int l = t & 63;
  const int r16 = l & 15;
  const int c4 = l >> 4;

  const int nx = gridDim.x;
  const int lin = xcd_swizzle(blockIdx.y * nx + blockIdx.x, gridDim.x * gridDim.y);
  const int m0 = (lin / nx) * 128;
  const int n0 = (lin % nx) * 128;

  const int srow = t >> 3;                      // 0..31
  const int schunk = (t & 7) ^ ((t >> 3) & 7);  // pre-swizzled source chunk
  const unsigned short* gA = A + (size_t)(m0 + srow) * K + schunk * 8;
  const unsigned short* gB = B + (size_t)(n0 + srow) * K + schunk * 8;
  const int lbase = w * 512;

  const int wm = (w >> 1) * 64;
  const int wn = (w & 1) * 64;

  f32x4 acc[4][4] = {};

  for (int k0 = 0; k0 < K; k0 += 64) {
#pragma unroll
    for (int i = 0; i < 4; ++i) {
      GLOAD_LDS16(gA + k0 + (size_t)i * 32 * K, &As[lbase + i * 2048]);
      GLOAD_LDS16(gB + k0 + (size_t)i * 32 * K, &Bs[lbase + i * 2048]);
    }
    __syncthreads();
#pragma unroll
    for (int kk = 0; kk < 2; ++kk) {
      bf16x8 af[4], bfr[4];
#pragma unroll
      for (int mi = 0; mi < 4; ++mi) {
        const int R = wm + mi * 16 + r16;
        const int ch = (kk * 4 + c4) ^ (R & 7);
        af[mi] = *reinterpret_cast<const bf16x8*>(&As[R * 64 + ch * 8]);
      }
#pragma unroll
      for (int ni = 0; ni < 4; ++ni) {
        const int R = wn + ni * 16 + r16;
        const int ch = (kk * 4 + c4) ^ (R & 7);
        bfr[ni] = *reinterpret_cast<const bf16x8*>(&Bs[R * 64 + ch * 8]);
      }
#pragma unroll
      for (int mi = 0; mi < 4; ++mi)
#pragma unroll
        for (int ni = 0; ni < 4; ++ni)
          acc[mi][ni] = __builtin_amdgcn_mfma_f32_16x16x32_bf16(af[mi], bfr[ni], acc[mi][ni], 0, 0, 0);
    }
    __syncthreads();
  }

  // epilogue: C/D layout col=lane&15, row=(lane>>4)*4+reg (m89/m91 verified)
  const int rbase = c4 * 4;
#pragma unroll
  for (int mi = 0; mi < 4; ++mi) {
    const int row = m0 + wm + mi * 16 + rbase;
#pragma unroll
    for (int ni = 0; ni < 4; ++ni) {
      const int col = n0 + wn + ni * 16 + r16;
      float bv = 0.0f;
      if constexpr (BIAS) bv = bias[col];
      f32x4 v = acc[mi][ni];
#pragma unroll
      for (int r = 0; r < 4; ++r) {
        float x = v[r] + bv;
        if constexpr (PHI_COLS > 0) {
          if (col < PHI_COLS) x = (x > 0.0f) ? (x + 1.0f) : __expf(x);  // elu+1
        }
        if constexpr (OUT_BF16)
          ((unsigned short*)Cout)[(size_t)(row + r) * N + col] = f2bf(x);
        else
          ((float*)Cout)[(size_t)(row + r) * N + col] = x;
      }
    }
  }
}

// ============================================================================
// kv[m,d] = sum_n k[n,d]*v[n,m]; ksum[d] = sum_n k[n,d].
// 16 chunks of 256 n per (b,h). LDS-f32 staging: each 64-n sub-tile of k,v is
// loaded+converted ONCE per block (vs 16x redundant cvt and 4x L1/L2 re-read
// per wave before): inner loop = 2 broadcast ds_read_b128 + 20 VALU per n.
// LDS 32KB. Output layout identical to previous version.
// ============================================================================
__global__ __launch_bounds__(256) void kv_partial_kernel(
    const unsigned short* __restrict__ qkv, float* __restrict__ kv_part,
    float* __restrict__ ksum_part) {
  __shared__ float ks32[64][64];  // [n][d] f32, 16KB
  __shared__ float vs32[64][64];  // [n][m] f32, 16KB
  const int bh = blockIdx.x;     // 48
  const int chunk = blockIdx.y;  // 16 (256 n each)
  const int b = bh / 12, h = bh % 12;
  const int t = threadIdx.x;
  const int tm = (t >> 4) * 4;
  const int td = (t & 15) * 4;
  const unsigned short* base =
      qkv + ((size_t)(b * 4096 + chunk * 256)) * 2304 + h * 64;

  float acc[4][4] = {};
  float ks[4] = {};

  for (int sub = 0; sub < 4; ++sub) {
    // stage 64 n x 64 d of k and v as f32 (each value cvt'd once per block)
#pragma unroll
    for (int s = t; s < 512; s += 256) {
      const int nl = s >> 3;        // 0..63 local row
      const int oct = s & 7;        // 8-short column octet
      const unsigned short* row = base + (size_t)(sub * 64 + nl) * 2304 + oct * 8;
      bf16x8 ku = *reinterpret_cast<const bf16x8*>(row + 768);   // k
      bf16x8 vu = *reinterpret_cast<const bf16x8*>(row + 1536);  // v
      float* kd = &ks32[nl][oct * 8];
      float* vd = &vs32[nl][oct * 8];
#pragma unroll
      for (int j = 0; j < 8; ++j) {
        kd[j] = bf2f((unsigned short)ku[j]);
        vd[j] = bf2f((unsigned short)vu[j]);
      }
    }
    __syncthreads();
#pragma unroll 8
    for (int n = 0; n < 64; ++n) {
      float4 kf = *reinterpret_cast<const float4*>(&ks32[n][td]);
      float4 vf = *reinterpret_cast<const float4*>(&vs32[n][tm]);
      const float ka[4] = {kf.x, kf.y, kf.z, kf.w};
      const float va[4] = {vf.x, vf.y, vf.z, vf.w};
#pragma unroll
      for (int i = 0; i < 4; ++i)
#pragma unroll
        for (int j = 0; j < 4; ++j) acc[i][j] += va[i] * ka[j];
#pragma unroll
      for (int j = 0; j < 4; ++j) ks[j] += ka[j];
    }
    __syncthreads();
  }

  float* kvp = kv_part + ((size_t)(bh * 16 + chunk)) * 4096;
#pragma unroll
  for (int i = 0; i < 4; ++i)
#pragma unroll
    for (int j = 0; j < 4; ++j) kvp[(tm + i) * 64 + td + j] = acc[i][j];
  if (tm == 0) {
    float* ksp = ksum_part + (size_t)(bh * 16 + chunk) * 64;
#pragma unroll
    for (int j = 0; j < 4; ++j) ksp[td + j] = ks[j];
  }
}

// widened reduce: grid (48,4); float4 loads; kv emitted bf16, ksum f32.
__global__ __launch_bounds__(256) void kv_reduce_kernel(
    const float* __restrict__ kv_part, const float* __restrict__ ksum_part,
    unsigned short* __restrict__ kvb, float* __restrict__ ksum) {
  const int bh = blockIdx.x;
  const int seg = blockIdx.y;
  const int t = threadIdx.x;
  const int e = seg * 1024 + t * 4;
  float4 s = {0.f, 0.f, 0.f, 0.f};
#pragma unroll
  for (int c = 0; c < 16; ++c) {
    float4 v = *reinterpret_cast<const float4*>(
        &kv_part[((size_t)(bh * 16 + c)) * 4096 + e]);
    s.x += v.x; s.y += v.y; s.z += v.z; s.w += v.w;
  }
  ushort4 o;
  o.x = f2bf(s.x); o.y = f2bf(s.y); o.z = f2bf(s.z); o.w = f2bf(s.w);
  *reinterpret_cast<ushort4*>(&kvb[(size_t)bh * 4096 + e]) = o;
  if (seg == 0 && t < 64) {
    float ss = 0.f;
#pragma unroll
    for (int c = 0; c < 16; ++c) ss += ksum_part[(size_t)(bh * 16 + c) * 64 + t];
    ksum[bh * 64 + t] = ss;
  }
}

// y[n,m] = z[n] * sum_d q[n,d] kv[m,d], z[n]=1/(q[n,:].ksum+eps), via MFMA.
__global__ __launch_bounds__(256) void y_mfma_kernel(
    const unsigned short* __restrict__ qkv, const unsigned short* __restrict__ kvb,
    const float* __restrict__ ksum, unsigned short* __restrict__ ybf) {
  __shared__ unsigned short Qs[128 * 64];
  __shared__ unsigned short KVs[64 * 64];
  __shared__ float zs[128];
  const int bh = blockIdx.x;
  const int n0 = blockIdx.y * 128;
  const int b = bh / 12, h = bh % 12;
  const int t = threadIdx.x;
  const int w = t >> 6;
  const int l = t & 63;
  const int r16 = l & 15;
  const int c4 = l >> 4;

  const int srow = t >> 3;
  const int schunk = (t & 7) ^ ((t >> 3) & 7);
  const unsigned short* gQ =
      qkv + ((size_t)(b * 4096 + n0 + srow)) * 2304 + h * 64 + schunk * 8;
  const unsigned short* gKV = kvb + (size_t)bh * 4096 + srow * 64 + schunk * 8;
  const int lbase = w * 512;
#pragma unroll
  for (int i = 0; i < 4; ++i)
    GLOAD_LDS16(gQ + (size_t)i * 32 * 2304, &Qs[lbase + i * 2048]);
#pragma unroll
  for (int i = 0; i < 2; ++i)
    GLOAD_LDS16(gKV + i * 32 * 64, &KVs[lbase + i * 2048]);
  __syncthreads();

  const int wr = w * 32;
  f32x4 acc[2][4] = {};
#pragma unroll
  for (int kk = 0; kk < 2; ++kk) {
    bf16x8 af[2], bfr[4];
#pragma unroll
    for (int mi = 0; mi < 2; ++mi) {
      const int R = wr + mi * 16 + r16;
      const int ch = (kk * 4 + c4) ^ (R & 7);
      af[mi] = *reinterpret_cast<const bf16x8*>(&Qs[R * 64 + ch * 8]);
    }
#pragma unroll
    for (int ni = 0; ni < 4; ++ni) {
      const int R = ni * 16 + r16;
      const int ch = (kk * 4 + c4) ^ (R & 7);
      bfr[ni] = *reinterpret_cast<const bf16x8*>(&KVs[R * 64 + ch * 8]);
    }
#pragma unroll
    for (int mi = 0; mi < 2; ++mi)
#pragma unroll
      for (int ni = 0; ni < 4; ++ni)
        acc[mi][ni] = __builtin_amdgcn_mfma_f32_16x16x32_bf16(af[mi], bfr[ni], acc[mi][ni], 0, 0, 0);
  }

  if (t < 128) {
    const float* ks = ksum + bh * 64;
    float s = 0.f;
#pragma unroll
    for (int c = 0; c < 8; ++c) {
      bf16x8 qv = *reinterpret_cast<const bf16x8*>(&Qs[t * 64 + ((c ^ (t & 7)) * 8)]);
#pragma unroll
      for (int j = 0; j < 8; ++j) s += bf2f((unsigned short)qv[j]) * ks[c * 8 + j];
    }
    zs[t] = 1.0f / (s + 1e-6f);
  }
  __syncthreads();

  unsigned short* ybase = ybf + ((size_t)(b * 4096 + n0)) * 768 + h * 64;
#pragma unroll
  for (int mi = 0; mi < 2; ++mi) {
#pragma unroll
    for (int ni = 0; ni < 4; ++ni) {
      const int col = ni * 16 + r16;
      f32x4 v = acc[mi][ni];
#pragma unroll
      for (int r = 0; r < 4; ++r) {
        const int row = wr + mi * 16 + c4 * 4 + r;
        ybase[(size_t)row * 768 + col] = f2bf(v[r] * zs[row]);
      }
    }
  }
}

extern "C" void kernel_launch(void* const* d_in, const int* in_sizes, int n_in,
                              void* d_out, int out_size, void* d_ws, size_t ws_size,
                              hipStream_t stream) {
  const float* x = (const float*)d_in[0];
  const float* Wqkv = (const float*)d_in[1];
  const float* Wproj = (const float*)d_in[2];
  const float* bproj = (const float*)d_in[3];
  float* out = (float*)d_out;

  const int M = 16384;
  const int C = 768;
  const int N1 = 2304;

  char* ws = (char*)d_ws;
  size_t off = 0;
  unsigned short* xb = (unsigned short*)(ws + off);  off += (size_t)M * C * 2;
  unsigned short* wqb = (unsigned short*)(ws + off); off += (size_t)N1 * C * 2;
  unsigned short* wpb = (unsigned short*)(ws + off); off += (size_t)C * C * 2;
  unsigned short* qkvb = (unsigned short*)(ws + off); off += (size_t)M * N1 * 2;
  unsigned short* kvb = (unsigned short*)(ws + off); off += (size_t)48 * 4096 * 2;
  float* ksum = (float*)(ws + off);      off += (size_t)48 * 64 * 4;
  unsigned short* yb = (unsigned short*)(ws + off); off += (size_t)M * C * 2;
  float* ksum_part = (float*)(ws + off); off += (size_t)48 * 16 * 64 * 4;
  float* kv_part = (float*)xb;  // overlays xb (dead after GEMM1); 12.6MB < 25MB

  const int na4 = M * C / 4, nb4 = N1 * C / 4, nc4 = C * C / 4;
  cast3_kernel<<<(na4 + nb4 + nc4 + 255) / 256, 256, 0, stream>>>(
      x, Wqkv, Wproj, xb, wqb, wpb, na4, nb4, nc4);

  // qkv = x @ Wqkv^T, phi fused on q,k columns, bf16 out
  gemm128<1536, true, false>
      <<<dim3(N1 / 128, M / 128), 256, 0, stream>>>(xb, wqb, qkvb, nullptr, M, N1, C);

  kv_partial_kernel<<<dim3(48, 16), 256, 0, stream>>>(qkvb, kv_part, ksum_part);
  kv_reduce_kernel<<<dim3(48, 4), 256, 0, stream>>>(kv_part, ksum_part, kvb, ksum);
  y_mfma_kernel<<<dim3(48, 32), 256, 0, stream>>>(qkvb, kvb, ksum, yb);

  // out = y @ Wproj^T + b, fp32 out
  gemm128<0, false, true>
      <<<dim3(C / 128, M / 128), 256, 0, stream>>>(yb, wpb, out, bproj, M, C, C);
}

// Round 15
// 156.353 us; speedup vs baseline: 1.2166x; 1.0015x over previous
//
#include <hip/hip_runtime.h>
#include <cstdint>
#include <cstddef>

// Linear attention: B=4 N=4096 C=768 H=12 d=64
// Pipeline: fused cast->bf16, GEMM1 128x128 BK=64 m97-style (x@Wqkv^T, fused
// phi), kv/ksum partials (16 chunks, LDS-f32-staged, packed f32 FMA), widened
// reduce (kv->bf16), y via MFMA, GEMM2 128x128 BK=64 (y@Wproj^T + bias).
//
// Schedule ledger (GEMM1 unless noted): BK=64 2-barrier = 92us BEATS
// 8-phase(118), 1-region ring(114), cross-buffer dbuf(103), BK=32(108),
// kk-split 8-phase(113), BK=96(GEMM2 +8us). Keep the 2-barrier loop.
// kv_partial ledger: LDS-f32 staging -25us (r13); f16 fdot2 FAILED numerics
// (r14, absmax 7.9e-2) -- v_dot2_f32_f16 is not full-precision; f32 pk only.

typedef __attribute__((ext_vector_type(8))) short bf16x8;
typedef __attribute__((ext_vector_type(4))) float f32x4;
typedef __attribute__((ext_vector_type(2))) float f32x2;

__device__ __forceinline__ unsigned short f2bf(float f) {
  uint32_t u = __builtin_bit_cast(uint32_t, f);
  u += 0x7FFFu + ((u >> 16) & 1u);  // RNE
  return (unsigned short)(u >> 16);
}
__device__ __forceinline__ float bf2f(unsigned short h) {
  uint32_t u = ((uint32_t)h) << 16;
  return __builtin_bit_cast(float, u);
}

__global__ __launch_bounds__(256) void cast3_kernel(
    const float* __restrict__ a, const float* __restrict__ b,
    const float* __restrict__ c, unsigned short* __restrict__ oa,
    unsigned short* __restrict__ ob, unsigned short* __restrict__ oc,
    int na4, int nb4, int nc4) {
  int i = blockIdx.x * 256 + threadIdx.x;
  const float* src;
  unsigned short* dst;
  if (i < na4) {
    src = a; dst = oa;
  } else if (i < na4 + nb4) {
    i -= na4; src = b; dst = ob;
  } else if (i < na4 + nb4 + nc4) {
    i -= na4 + nb4; src = c; dst = oc;
  } else {
    return;
  }
  float4 v = reinterpret_cast<const float4*>(src)[i];
  ushort4 o;
  o.x = f2bf(v.x); o.y = f2bf(v.y); o.z = f2bf(v.z); o.w = f2bf(v.w);
  reinterpret_cast<ushort4*>(dst)[i] = o;
}

#define GLOAD_LDS16(g, s)                                                     \
  __builtin_amdgcn_global_load_lds(                                           \
      (const __attribute__((address_space(1))) void*)(g),                     \
      (__attribute__((address_space(3))) void*)(s), 16, 0, 0)

__device__ __forceinline__ int xcd_swizzle(int lin, int nwg) {
  const int q = nwg >> 3, r = nwg & 7;
  const int xcd = lin & 7, idx = lin >> 3;
  return (xcd < r ? xcd * (q + 1) : r * (q + 1) + (xcd - r) * q) + idx;
}

// ============================================================================
// PROVEN: 128x128 tile, BK=64, 4 waves (2x2 of 64x64), 4x4 16x16x32 frags,
// global_load_lds width-16, plain __syncthreads (2/K-step), multi-block
// co-residency hides the barrier drain (m114). XOR chunk swizzle both-sides
// (rule #21), bijective XCD swizzle (m204).
// ============================================================================
template <int PHI_COLS, bool OUT_BF16, bool BIAS>
__global__ __launch_bounds__(256) void gemm128(
    const unsigned short* __restrict__ A, const unsigned short* __restrict__ B,
    void* __restrict__ Cout, const float* __restrict__ bias, int M, int N, int K) {
  __shared__ unsigned short As[128 * 64];
  __shared__ unsigned short Bs[128 * 64];
  const int t = threadIdx.x;
  const int w = t >> 6;
  const int l = t & 63;
  const int r16 = l & 15;
  const int c4 = l >> 4;

  const int nx = gridDim.x;
  const int lin = xcd_swizzle(blockIdx.y * nx + blockIdx.x, gridDim.x * gridDim.y);
  const int m0 = (lin / nx) * 128;
  const int n0 = (lin % nx) * 128;

  const int srow = t >> 3;                      // 0..31
  const int schunk = (t & 7) ^ ((t >> 3) & 7);  // pre-swizzled source chunk
  const unsigned short* gA = A + (size_t)(m0 + srow) * K + schunk * 8;
  const unsigned short* gB = B + (size_t)(n0 + srow) * K + schunk * 8;
  const int lbase = w * 512;

  const int wm = (w >> 1) * 64;
  const int wn = (w & 1) * 64;

  f32x4 acc[4][4] = {};

  for (int k0 = 0; k0 < K; k0 += 64) {
#pragma unroll
    for (int i = 0; i < 4; ++i) {
      GLOAD_LDS16(gA + k0 + (size_t)i * 32 * K, &As[lbase + i * 2048]);
      GLOAD_LDS16(gB + k0 + (size_t)i * 32 * K, &Bs[lbase + i * 2048]);
    }
    __syncthreads();
#pragma unroll
    for (int kk = 0; kk < 2; ++kk) {
      bf16x8 af[4], bfr[4];
#pragma unroll
      for (int mi = 0; mi < 4; ++mi) {
        const int R = wm + mi * 16 + r16;
        const int ch = (kk * 4 + c4) ^ (R & 7);
        af[mi] = *reinterpret_cast<const bf16x8*>(&As[R * 64 + ch * 8]);
      }
#pragma unroll
      for (int ni = 0; ni < 4; ++ni) {
        const int R = wn + ni * 16 + r16;
        const int ch = (kk * 4 + c4) ^ (R & 7);
        bfr[ni] = *reinterpret_cast<const bf16x8*>(&Bs[R * 64 + ch * 8]);
      }
#pragma unroll
      for (int mi = 0; mi < 4; ++mi)
#pragma unroll
        for (int ni = 0; ni < 4; ++ni)
          acc[mi][ni] = __builtin_amdgcn_mfma_f32_16x16x32_bf16(af[mi], bfr[ni], acc[mi][ni], 0, 0, 0);
    }
    __syncthreads();
  }

  // epilogue: C/D layout col=lane&15, row=(lane>>4)*4+reg (m89/m91 verified)
  const int rbase = c4 * 4;
#pragma unroll
  for (int mi = 0; mi < 4; ++mi) {
    const int row = m0 + wm + mi * 16 + rbase;
#pragma unroll
    for (int ni = 0; ni < 4; ++ni) {
      const int col = n0 + wn + ni * 16 + r16;
      float bv = 0.0f;
      if constexpr (BIAS) bv = bias[col];
      f32x4 v = acc[mi][ni];
#pragma unroll
      for (int r = 0; r < 4; ++r) {
        float x = v[r] + bv;
        if constexpr (PHI_COLS > 0) {
          if (col < PHI_COLS) x = (x > 0.0f) ? (x + 1.0f) : __expf(x);  // elu+1
        }
        if constexpr (OUT_BF16)
          ((unsigned short*)Cout)[(size_t)(row + r) * N + col] = f2bf(x);
        else
          ((float*)Cout)[(size_t)(row + r) * N + col] = x;
      }
    }
  }
}

// ============================================================================
// kv[m,d] = sum_n k[n,d]*v[n,m]; ksum[d] = sum_n k[n,d].
// 16 chunks of 256 n per (b,h). LDS-f32 staging (cvt once per block, r13's
// -25us win). Inner loop on float2 vectors: identical IEEE f32 FMA math
// (bit-exact vs r13) but lets the backend emit v_pk_fma_f32 (2 FMA/instr,
// FeaturePackedFP32Ops on gfx950) -> VALU per n ~20 -> ~14. Worst case it
// scalarizes and exactly reproduces r13.  (f16 fdot2 path REMOVED: r14
// showed v_dot2_f32_f16 is not full-precision -> absmax 7.9e-2 fail.)
// ============================================================================
__global__ __launch_bounds__(256) void kv_partial_kernel(
    const unsigned short* __restrict__ qkv, float* __restrict__ kv_part,
    float* __restrict__ ksum_part) {
  __shared__ float ks32[64][64];  // [n][d] f32, 16KB
  __shared__ float vs32[64][64];  // [n][m] f32, 16KB
  const int bh = blockIdx.x;     // 48
  const int chunk = blockIdx.y;  // 16 (256 n each)
  const int b = bh / 12, h = bh % 12;
  const int t = threadIdx.x;
  const int tm = (t >> 4) * 4;
  const int td = (t & 15) * 4;
  const unsigned short* base =
      qkv + ((size_t)(b * 4096 + chunk * 256)) * 2304 + h * 64;

  f32x2 acc2[4][2] = {};  // [i][jj]: j = jj*2 + {0,1}
  f32x2 kss[2] = {};

  for (int sub = 0; sub < 4; ++sub) {
    // stage 64 n x 64 d of k and v as f32 (each value cvt'd once per block)
#pragma unroll
    for (int s = t; s < 512; s += 256) {
      const int nl = s >> 3;        // 0..63 local row
      const int oct = s & 7;        // 8-short column octet
      const unsigned short* row = base + (size_t)(sub * 64 + nl) * 2304 + oct * 8;
      bf16x8 ku = *reinterpret_cast<const bf16x8*>(row + 768);   // k
      bf16x8 vu = *reinterpret_cast<const bf16x8*>(row + 1536);  // v
      float* kd = &ks32[nl][oct * 8];
      float* vd = &vs32[nl][oct * 8];
#pragma unroll
      for (int j = 0; j < 8; ++j) {
        kd[j] = bf2f((unsigned short)ku[j]);
        vd[j] = bf2f((unsigned short)vu[j]);
      }
    }
    __syncthreads();
#pragma unroll 8
    for (int n = 0; n < 64; ++n) {
      float4 kf = *reinterpret_cast<const float4*>(&ks32[n][td]);
      float4 vf = *reinterpret_cast<const float4*>(&vs32[n][tm]);
      f32x2 k0; k0[0] = kf.x; k0[1] = kf.y;   // aligned pair from b128 result
      f32x2 k1; k1[0] = kf.z; k1[1] = kf.w;
      const float va[4] = {vf.x, vf.y, vf.z, vf.w};
#pragma unroll
      for (int i = 0; i < 4; ++i) {
        f32x2 vd2; vd2[0] = va[i]; vd2[1] = va[i];
        acc2[i][0] += vd2 * k0;  // v_pk_fma_f32 candidate
        acc2[i][1] += vd2 * k1;
      }
      kss[0] += k0;
      kss[1] += k1;
    }
    __syncthreads();
  }

  float* kvp = kv_part + ((size_t)(bh * 16 + chunk)) * 4096;
#pragma unroll
  for (int i = 0; i < 4; ++i) {
    float4 o;
    o.x = acc2[i][0][0]; o.y = acc2[i][0][1];
    o.z = acc2[i][1][0]; o.w = acc2[i][1][1];
    *reinterpret_cast<float4*>(&kvp[(tm + i) * 64 + td]) = o;
  }
  if (tm == 0) {
    float* ksp = ksum_part + (size_t)(bh * 16 + chunk) * 64;
    float4 o;
    o.x = kss[0][0]; o.y = kss[0][1]; o.z = kss[1][0]; o.w = kss[1][1];
    *reinterpret_cast<float4*>(&ksp[td]) = o;
  }
}

// widened reduce: grid (48,4); float4 loads; kv emitted bf16, ksum f32.
__global__ __launch_bounds__(256) void kv_reduce_kernel(
    const float* __restrict__ kv_part, const float* __restrict__ ksum_part,
    unsigned short* __restrict__ kvb, float* __restrict__ ksum) {
  const int bh = blockIdx.x;
  const int seg = blockIdx.y;
  const int t = threadIdx.x;
  const int e = seg * 1024 + t * 4;
  float4 s = {0.f, 0.f, 0.f, 0.f};
#pragma unroll
  for (int c = 0; c < 16; ++c) {
    float4 v = *reinterpret_cast<const float4*>(
        &kv_part[((size_t)(bh * 16 + c)) * 4096 + e]);
    s.x += v.x; s.y += v.y; s.z += v.z; s.w += v.w;
  }
  ushort4 o;
  o.x = f2bf(s.x); o.y = f2bf(s.y); o.z = f2bf(s.z); o.w = f2bf(s.w);
  *reinterpret_cast<ushort4*>(&kvb[(size_t)bh * 4096 + e]) = o;
  if (seg == 0 && t < 64) {
    float ss = 0.f;
#pragma unroll
    for (int c = 0; c < 16; ++c) ss += ksum_part[(size_t)(bh * 16 + c) * 64 + t];
    ksum[bh * 64 + t] = ss;
  }
}

// y[n,m] = z[n] * sum_d q[n,d] kv[m,d], z[n]=1/(q[n,:].ksum+eps), via MFMA.
__global__ __launch_bounds__(256) void y_mfma_kernel(
    const unsigned short* __restrict__ qkv, const unsigned short* __restrict__ kvb,
    const float* __restrict__ ksum, unsigned short* __restrict__ ybf) {
  __shared__ unsigned short Qs[128 * 64];
  __shared__ unsigned short KVs[64 * 64];
  __shared__ float zs[128];
  const int bh = blockIdx.x;
  const int n0 = blockIdx.y * 128;
  const int b = bh / 12, h = bh % 12;
  const int t = threadIdx.x;
  const int w = t >> 6;
  const int l = t & 63;
  const int r16 = l & 15;
  const int c4 = l >> 4;

  const int srow = t >> 3;
  const int schunk = (t & 7) ^ ((t >> 3) & 7);
  const unsigned short* gQ =
      qkv + ((size_t)(b * 4096 + n0 + srow)) * 2304 + h * 64 + schunk * 8;
  const unsigned short* gKV = kvb + (size_t)bh * 4096 + srow * 64 + schunk * 8;
  const int lbase = w * 512;
#pragma unroll
  for (int i = 0; i < 4; ++i)
    GLOAD_LDS16(gQ + (size_t)i * 32 * 2304, &Qs[lbase + i * 2048]);
#pragma unroll
  for (int i = 0; i < 2; ++i)
    GLOAD_LDS16(gKV + i * 32 * 64, &KVs[lbase + i * 2048]);
  __syncthreads();

  const int wr = w * 32;
  f32x4 acc[2][4] = {};
#pragma unroll
  for (int kk = 0; kk < 2; ++kk) {
    bf16x8 af[2], bfr[4];
#pragma unroll
    for (int mi = 0; mi < 2; ++mi) {
      const int R = wr + mi * 16 + r16;
      const int ch = (kk * 4 + c4) ^ (R & 7);
      af[mi] = *reinterpret_cast<const bf16x8*>(&Qs[R * 64 + ch * 8]);
    }
#pragma unroll
    for (int ni = 0; ni < 4; ++ni) {
      const int R = ni * 16 + r16;
      const int ch = (kk * 4 + c4) ^ (R & 7);
      bfr[ni] = *reinterpret_cast<const bf16x8*>(&KVs[R * 64 + ch * 8]);
    }
#pragma unroll
    for (int mi = 0; mi < 2; ++mi)
#pragma unroll
      for (int ni = 0; ni < 4; ++ni)
        acc[mi][ni] = __builtin_amdgcn_mfma_f32_16x16x32_bf16(af[mi], bfr[ni], acc[mi][ni], 0, 0, 0);
  }

  if (t < 128) {
    const float* ks = ksum + bh * 64;
    float s = 0.f;
#pragma unroll
    for (int c = 0; c < 8; ++c) {
      bf16x8 qv = *reinterpret_cast<const bf16x8*>(&Qs[t * 64 + ((c ^ (t & 7)) * 8)]);
#pragma unroll
      for (int j = 0; j < 8; ++j) s += bf2f((unsigned short)qv[j]) * ks[c * 8 + j];
    }
    zs[t] = 1.0f / (s + 1e-6f);
  }
  __syncthreads();

  unsigned short* ybase = ybf + ((size_t)(b * 4096 + n0)) * 768 + h * 64;
#pragma unroll
  for (int mi = 0; mi < 2; ++mi) {
#pragma unroll
    for (int ni = 0; ni < 4; ++ni) {
      const int col = ni * 16 + r16;
      f32x4 v = acc[mi][ni];
#pragma unroll
      for (int r = 0; r < 4; ++r) {
        const int row = wr + mi * 16 + c4 * 4 + r;
        ybase[(size_t)row * 768 + col] = f2bf(v[r] * zs[row]);
      }
    }
  }
}

extern "C" void kernel_launch(void* const* d_in, const int* in_sizes, int n_in,
                              void* d_out, int out_size, void* d_ws, size_t ws_size,
                              hipStream_t stream) {
  const float* x = (const float*)d_in[0];
  const float* Wqkv = (const float*)d_in[1];
  const float* Wproj = (const float*)d_in[2];
  const float* bproj = (const float*)d_in[3];
  float* out = (float*)d_out;

  const int M = 16384;
  const int C = 768;
  const int N1 = 2304;

  char* ws = (char*)d_ws;
  size_t off = 0;
  unsigned short* xb = (unsigned short*)(ws + off);  off += (size_t)M * C * 2;
  unsigned short* wqb = (unsigned short*)(ws + off); off += (size_t)N1 * C * 2;
  unsigned short* wpb = (unsigned short*)(ws + off); off += (size_t)C * C * 2;
  unsigned short* qkvb = (unsigned short*)(ws + off); off += (size_t)M * N1 * 2;
  unsigned short* kvb = (unsigned short*)(ws + off); off += (size_t)48 * 4096 * 2;
  float* ksum = (float*)(ws + off);      off += (size_t)48 * 64 * 4;
  unsigned short* yb = (unsigned short*)(ws + off); off += (size_t)M * C * 2;
  float* ksum_part = (float*)(ws + off); off += (size_t)48 * 16 * 64 * 4;
  float* kv_part = (float*)xb;  // overlays xb (dead after GEMM1); 12.6MB < 25MB

  const int na4 = M * C / 4, nb4 = N1 * C / 4, nc4 = C * C / 4;
  cast3_kernel<<<(na4 + nb4 + nc4 + 255) / 256, 256, 0, stream>>>(
      x, Wqkv, Wproj, xb, wqb, wpb, na4, nb4, nc4);

  // qkv = x @ Wqkv^T, phi fused on q,k columns, bf16 out
  gemm128<1536, true, false>
      <<<dim3(N1 / 128, M / 128), 256, 0, stream>>>(xb, wqb, qkvb, nullptr, M, N1, C);

  kv_partial_kernel<<<dim3(48, 16), 256, 0, stream>>>(qkvb, kv_part, ksum_part);
  kv_reduce_kernel<<<dim3(48, 4), 256, 0, stream>>>(kv_part, ksum_part, kvb, ksum);
  y_mfma_kernel<<<dim3(48, 32), 256, 0, stream>>>(qkvb, kvb, ksum, yb);

  // out = y @ Wproj^T + b, fp32 out
  gemm128<0, false, true>
      <<<dim3(C / 128, M / 128), 256, 0, stream>>>(yb, wpb, out, bproj, M, C, C);
}

// Round 16
// 145.036 us; speedup vs baseline: 1.3115x; 1.0780x over previous
//
#include <hip/hip_runtime.h>
#include <cstdint>
#include <cstddef>

// Linear attention: B=4 N=4096 C=768 H=12 d=64
// Pipeline: fused cast->bf16, GEMM1 128x128 BK=64 m97-style (x@Wqkv^T, fused
// phi), kv/ksum partials (16 chunks, LDS-f32-staged), widened reduce
// (kv->bf16), y via MFMA, GEMM2 128x128 BK=64 (y@Wproj^T + bias).
//
// Ledger: BK=64 2-barrier = 92us BEATS 8-phase(118), ring(114), dbuf(103),
// BK=32(108), kk-split(113), BK=96(+8). kv: LDS-f32 staging -25us (r13);
// fdot2 FAILED numerics (r14); f32x2 pack neutral (r15).
// r16 experiment: __launch_bounds__(256,4) on gemm128 — occupancy is
// REGISTER-capped (80 arch VGPR + 64 AGPR acc ~ 144/wave -> 3 blocks/CU,
// matches 29% occupancy; LDS would allow 5). Forcing 128 regs/wave -> 4
// blocks/CU -> better m114 drain-hiding. Bounded risk: spill = revert.

typedef __attribute__((ext_vector_type(8))) short bf16x8;
typedef __attribute__((ext_vector_type(4))) float f32x4;
typedef __attribute__((ext_vector_type(2))) float f32x2;

__device__ __forceinline__ unsigned short f2bf(float f) {
  uint32_t u = __builtin_bit_cast(uint32_t, f);
  u += 0x7FFFu + ((u >> 16) & 1u);  // RNE
  return (unsigned short)(u >> 16);
}
__device__ __forceinline__ float bf2f(unsigned short h) {
  uint32_t u = ((uint32_t)h) << 16;
  return __builtin_bit_cast(float, u);
}

__global__ __launch_bounds__(256) void cast3_kernel(
    const float* __restrict__ a, const float* __restrict__ b,
    const float* __restrict__ c, unsigned short* __restrict__ oa,
    unsigned short* __restrict__ ob, unsigned short* __restrict__ oc,
    int na4, int nb4, int nc4) {
  int i = blockIdx.x * 256 + threadIdx.x;
  const float* src;
  unsigned short* dst;
  if (i < na4) {
    src = a; dst = oa;
  } else if (i < na4 + nb4) {
    i -= na4; src = b; dst = ob;
  } else if (i < na4 + nb4 + nc4) {
    i -= na4 + nb4; src = c; dst = oc;
  } else {
    return;
  }
  float4 v = reinterpret_cast<const float4*>(src)[i];
  ushort4 o;
  o.x = f2bf(v.x); o.y = f2bf(v.y); o.z = f2bf(v.z); o.w = f2bf(v.w);
  reinterpret_cast<ushort4*>(dst)[i] = o;
}

#define GLOAD_LDS16(g, s)                                                     \
  __builtin_amdgcn_global_load_lds(                                           \
      (const __attribute__((address_space(1))) void*)(g),                     \
      (__attribute__((address_space(3))) void*)(s), 16, 0, 0)

__device__ __forceinline__ int xcd_swizzle(int lin, int nwg) {
  const int q = nwg >> 3, r = nwg & 7;
  const int xcd = lin & 7, idx = lin >> 3;
  return (xcd < r ? xcd * (q + 1) : r * (q + 1) + (xcd - r) * q) + idx;
}

// ============================================================================
// PROVEN structure + r16 occupancy bound: 128x128 tile, BK=64, 4 waves,
// 4x4 16x16x32 frags, global_load_lds width-16, plain __syncthreads
// (2/K-step), XOR chunk swizzle both-sides (rule #21), bijective XCD swizzle
// (m204). __launch_bounds__(256,4): cap 128 regs/wave -> 4 blocks/CU.
// ============================================================================
template <int PHI_COLS, bool OUT_BF16, bool BIAS>
__global__ __launch_bounds__(256, 4) void gemm128(
    const unsigned short* __restrict__ A, const unsigned short* __restrict__ B,
    void* __restrict__ Cout, const float* __restrict__ bias, int M, int N, int K) {
  __shared__ unsigned short As[128 * 64];
  __shared__ unsigned short Bs[128 * 64];
  const int t = threadIdx.x;
  const int w = t >> 6;
  const int l = t & 63;
  const int r16 = l & 15;
  const int c4 = l >> 4;

  const int nx = gridDim.x;
  const int lin = xcd_swizzle(blockIdx.y * nx + blockIdx.x, gridDim.x * gridDim.y);
  const int m0 = (lin / nx) * 128;
  const int n0 = (lin % nx) * 128;

  const int srow = t >> 3;                      // 0..31
  const int schunk = (t & 7) ^ ((t >> 3) & 7);  // pre-swizzled source chunk
  const unsigned short* gA = A + (size_t)(m0 + srow) * K + schunk * 8;
  const unsigned short* gB = B + (size_t)(n0 + srow) * K + schunk * 8;
  const int lbase = w * 512;

  const int wm = (w >> 1) * 64;
  const int wn = (w & 1) * 64;

  f32x4 acc[4][4] = {};

  for (int k0 = 0; k0 < K; k0 += 64) {
#pragma unroll
    for (int i = 0; i < 4; ++i) {
      GLOAD_LDS16(gA + k0 + (size_t)i * 32 * K, &As[lbase + i * 2048]);
      GLOAD_LDS16(gB + k0 + (size_t)i * 32 * K, &Bs[lbase + i * 2048]);
    }
    __syncthreads();
#pragma unroll
    for (int kk = 0; kk < 2; ++kk) {
      bf16x8 af[4], bfr[4];
#pragma unroll
      for (int mi = 0; mi < 4; ++mi) {
        const int R = wm + mi * 16 + r16;
        const int ch = (kk * 4 + c4) ^ (R & 7);
        af[mi] = *reinterpret_cast<const bf16x8*>(&As[R * 64 + ch * 8]);
      }
#pragma unroll
      for (int ni = 0; ni < 4; ++ni) {
        const int R = wn + ni * 16 + r16;
        const int ch = (kk * 4 + c4) ^ (R & 7);
        bfr[ni] = *reinterpret_cast<const bf16x8*>(&Bs[R * 64 + ch * 8]);
      }
#pragma unroll
      for (int mi = 0; mi < 4; ++mi)
#pragma unroll
        for (int ni = 0; ni < 4; ++ni)
          acc[mi][ni] = __builtin_amdgcn_mfma_f32_16x16x32_bf16(af[mi], bfr[ni], acc[mi][ni], 0, 0, 0);
    }
    __syncthreads();
  }

  // epilogue: C/D layout col=lane&15, row=(lane>>4)*4+reg (m89/m91 verified)
  const int rbase = c4 * 4;
#pragma unroll
  for (int mi = 0; mi < 4; ++mi) {
    const int row = m0 + wm + mi * 16 + rbase;
#pragma unroll
    for (int ni = 0; ni < 4; ++ni) {
      const int col = n0 + wn + ni * 16 + r16;
      float bv = 0.0f;
      if constexpr (BIAS) bv = bias[col];
      f32x4 v = acc[mi][ni];
#pragma unroll
      for (int r = 0; r < 4; ++r) {
        float x = v[r] + bv;
        if constexpr (PHI_COLS > 0) {
          if (col < PHI_COLS) x = (x > 0.0f) ? (x + 1.0f) : __expf(x);  // elu+1
        }
        if constexpr (OUT_BF16)
          ((unsigned short*)Cout)[(size_t)(row + r) * N + col] = f2bf(x);
        else
          ((float*)Cout)[(size_t)(row + r) * N + col] = x;
      }
    }
  }
}

// ============================================================================
// kv[m,d] = sum_n k[n,d]*v[n,m]; ksum[d] = sum_n k[n,d].
// 16 chunks of 256 n per (b,h). LDS-f32 staging (cvt once per block).
// ============================================================================
__global__ __launch_bounds__(256) void kv_partial_kernel(
    const unsigned short* __restrict__ qkv, float* __restrict__ kv_part,
    float* __restrict__ ksum_part) {
  __shared__ float ks32[64][64];  // [n][d] f32, 16KB
  __shared__ float vs32[64][64];  // [n][m] f32, 16KB
  const int bh = blockIdx.x;     // 48
  const int chunk = blockIdx.y;  // 16 (256 n each)
  const int b = bh / 12, h = bh % 12;
  const int t = threadIdx.x;
  const int tm = (t >> 4) * 4;
  const int td = (t & 15) * 4;
  const unsigned short* base =
      qkv + ((size_t)(b * 4096 + chunk * 256)) * 2304 + h * 64;

  f32x2 acc2[4][2] = {};
  f32x2 kss[2] = {};

  for (int sub = 0; sub < 4; ++sub) {
#pragma unroll
    for (int s = t; s < 512; s += 256) {
      const int nl = s >> 3;
      const int oct = s & 7;
      const unsigned short* row = base + (size_t)(sub * 64 + nl) * 2304 + oct * 8;
      bf16x8 ku = *reinterpret_cast<const bf16x8*>(row + 768);   // k
      bf16x8 vu = *reinterpret_cast<const bf16x8*>(row + 1536);  // v
      float* kd = &ks32[nl][oct * 8];
      float* vd = &vs32[nl][oct * 8];
#pragma unroll
      for (int j = 0; j < 8; ++j) {
        kd[j] = bf2f((unsigned short)ku[j]);
        vd[j] = bf2f((unsigned short)vu[j]);
      }
    }
    __syncthreads();
#pragma unroll 8
    for (int n = 0; n < 64; ++n) {
      float4 kf = *reinterpret_cast<const float4*>(&ks32[n][td]);
      float4 vf = *reinterpret_cast<const float4*>(&vs32[n][tm]);
      f32x2 k0; k0[0] = kf.x; k0[1] = kf.y;
      f32x2 k1; k1[0] = kf.z; k1[1] = kf.w;
      const float va[4] = {vf.x, vf.y, vf.z, vf.w};
#pragma unroll
      for (int i = 0; i < 4; ++i) {
        f32x2 vd2; vd2[0] = va[i]; vd2[1] = va[i];
        acc2[i][0] += vd2 * k0;
        acc2[i][1] += vd2 * k1;
      }
      kss[0] += k0;
      kss[1] += k1;
    }
    __syncthreads();
  }

  float* kvp = kv_part + ((size_t)(bh * 16 + chunk)) * 4096;
#pragma unroll
  for (int i = 0; i < 4; ++i) {
    float4 o;
    o.x = acc2[i][0][0]; o.y = acc2[i][0][1];
    o.z = acc2[i][1][0]; o.w = acc2[i][1][1];
    *reinterpret_cast<float4*>(&kvp[(tm + i) * 64 + td]) = o;
  }
  if (tm == 0) {
    float* ksp = ksum_part + (size_t)(bh * 16 + chunk) * 64;
    float4 o;
    o.x = kss[0][0]; o.y = kss[0][1]; o.z = kss[1][0]; o.w = kss[1][1];
    *reinterpret_cast<float4*>(&ksp[td]) = o;
  }
}

// widened reduce: grid (48,4); float4 loads; kv emitted bf16, ksum f32.
__global__ __launch_bounds__(256) void kv_reduce_kernel(
    const float* __restrict__ kv_part, const float* __restrict__ ksum_part,
    unsigned short* __restrict__ kvb, float* __restrict__ ksum) {
  const int bh = blockIdx.x;
  const int seg = blockIdx.y;
  const int t = threadIdx.x;
  const int e = seg * 1024 + t * 4;
  float4 s = {0.f, 0.f, 0.f, 0.f};
#pragma unroll
  for (int c = 0; c < 16; ++c) {
    float4 v = *reinterpret_cast<const float4*>(
        &kv_part[((size_t)(bh * 16 + c)) * 4096 + e]);
    s.x += v.x; s.y += v.y; s.z += v.z; s.w += v.w;
  }
  ushort4 o;
  o.x = f2bf(s.x); o.y = f2bf(s.y); o.z = f2bf(s.z); o.w = f2bf(s.w);
  *reinterpret_cast<ushort4*>(&kvb[(size_t)bh * 4096 + e]) = o;
  if (seg == 0 && t < 64) {
    float ss = 0.f;
#pragma unroll
    for (int c = 0; c < 16; ++c) ss += ksum_part[(size_t)(bh * 16 + c) * 64 + t];
    ksum[bh * 64 + t] = ss;
  }
}

// y[n,m] = z[n] * sum_d q[n,d] kv[m,d], z[n]=1/(q[n,:].ksum+eps), via MFMA.
__global__ __launch_bounds__(256) void y_mfma_kernel(
    const unsigned short* __restrict__ qkv, const unsigned short* __restrict__ kvb,
    const float* __restrict__ ksum, unsigned short* __restrict__ ybf) {
  __shared__ unsigned short Qs[128 * 64];
  __shared__ unsigned short KVs[64 * 64];
  __shared__ float zs[128];
  const int bh = blockIdx.x;
  const int n0 = blockIdx.y * 128;
  const int b = bh / 12, h = bh % 12;
  const int t = threadIdx.x;
  const int w = t >> 6;
  const int l = t & 63;
  const int r16 = l & 15;
  const int c4 = l >> 4;

  const int srow = t >> 3;
  const int schunk = (t & 7) ^ ((t >> 3) & 7);
  const unsigned short* gQ =
      qkv + ((size_t)(b * 4096 + n0 + srow)) * 2304 + h * 64 + schunk * 8;
  const unsigned short* gKV = kvb + (size_t)bh * 4096 + srow * 64 + schunk * 8;
  const int lbase = w * 512;
#pragma unroll
  for (int i = 0; i < 4; ++i)
    GLOAD_LDS16(gQ + (size_t)i * 32 * 2304, &Qs[lbase + i * 2048]);
#pragma unroll
  for (int i = 0; i < 2; ++i)
    GLOAD_LDS16(gKV + i * 32 * 64, &KVs[lbase + i * 2048]);
  __syncthreads();

  const int wr = w * 32;
  f32x4 acc[2][4] = {};
#pragma unroll
  for (int kk = 0; kk < 2; ++kk) {
    bf16x8 af[2], bfr[4];
#pragma unroll
    for (int mi = 0; mi < 2; ++mi) {
      const int R = wr + mi * 16 + r16;
      const int ch = (kk * 4 + c4) ^ (R & 7);
      af[mi] = *reinterpret_cast<const bf16x8*>(&Qs[R * 64 + ch * 8]);
    }
#pragma unroll
    for (int ni = 0; ni < 4; ++ni) {
      const int R = ni * 16 + r16;
      const int ch = (kk * 4 + c4) ^ (R & 7);
      bfr[ni] = *reinterpret_cast<const bf16x8*>(&KVs[R * 64 + ch * 8]);
    }
#pragma unroll
    for (int mi = 0; mi < 2; ++mi)
#pragma unroll
      for (int ni = 0; ni < 4; ++ni)
        acc[mi][ni] = __builtin_amdgcn_mfma_f32_16x16x32_bf16(af[mi], bfr[ni], acc[mi][ni], 0, 0, 0);
  }

  if (t < 128) {
    const float* ks = ksum + bh * 64;
    float s = 0.f;
#pragma unroll
    for (int c = 0; c < 8; ++c) {
      bf16x8 qv = *reinterpret_cast<const bf16x8*>(&Qs[t * 64 + ((c ^ (t & 7)) * 8)]);
#pragma unroll
      for (int j = 0; j < 8; ++j) s += bf2f((unsigned short)qv[j]) * ks[c * 8 + j];
    }
    zs[t] = 1.0f / (s + 1e-6f);
  }
  __syncthreads();

  unsigned short* ybase = ybf + ((size_t)(b * 4096 + n0)) * 768 + h * 64;
#pragma unroll
  for (int mi = 0; mi < 2; ++mi) {
#pragma unroll
    for (int ni = 0; ni < 4; ++ni) {
      const int col = ni * 16 + r16;
      f32x4 v = acc[mi][ni];
#pragma unroll
      for (int r = 0; r < 4; ++r) {
        const int row = wr + mi * 16 + c4 * 4 + r;
        ybase[(size_t)row * 768 + col] = f2bf(v[r] * zs[row]);
      }
    }
  }
}

extern "C" void kernel_launch(void* const* d_in, const int* in_sizes, int n_in,
                              void* d_out, int out_size, void* d_ws, size_t ws_size,
                              hipStream_t stream) {
  const float* x = (const float*)d_in[0];
  const float* Wqkv = (const float*)d_in[1];
  const float* Wproj = (const float*)d_in[2];
  const float* bproj = (const float*)d_in[3];
  float* out = (float*)d_out;

  const int M = 16384;
  const int C = 768;
  const int N1 = 2304;

  char* ws = (char*)d_ws;
  size_t off = 0;
  unsigned short* xb = (unsigned short*)(ws + off);  off += (size_t)M * C * 2;
  unsigned short* wqb = (unsigned short*)(ws + off); off += (size_t)N1 * C * 2;
  unsigned short* wpb = (unsigned short*)(ws + off); off += (size_t)C * C * 2;
  unsigned short* qkvb = (unsigned short*)(ws + off); off += (size_t)M * N1 * 2;
  unsigned short* kvb = (unsigned short*)(ws + off); off += (size_t)48 * 4096 * 2;
  float* ksum = (float*)(ws + off);      off += (size_t)48 * 64 * 4;
  unsigned short* yb = (unsigned short*)(ws + off); off += (size_t)M * C * 2;
  float* ksum_part = (float*)(ws + off); off += (size_t)48 * 16 * 64 * 4;
  float* kv_part = (float*)xb;  // overlays xb (dead after GEMM1); 12.6MB < 25MB

  const int na4 = M * C / 4, nb4 = N1 * C / 4, nc4 = C * C / 4;
  cast3_kernel<<<(na4 + nb4 + nc4 + 255) / 256, 256, 0, stream>>>(
      x, Wqkv, Wproj, xb, wqb, wpb, na4, nb4, nc4);

  // qkv = x @ Wqkv^T, phi fused on q,k columns, bf16 out
  gemm128<1536, true, false>
      <<<dim3(N1 / 128, M / 128), 256, 0, stream>>>(xb, wqb, qkvb, nullptr, M, N1, C);

  kv_partial_kernel<<<dim3(48, 16), 256, 0, stream>>>(qkvb, kv_part, ksum_part);
  kv_reduce_kernel<<<dim3(48, 4), 256, 0, stream>>>(kv_part, ksum_part, kvb, ksum);
  y_mfma_kernel<<<dim3(48, 32), 256, 0, stream>>>(qkvb, kvb, ksum, yb);

  // out = y @ Wproj^T + b, fp32 out
  gemm128<0, false, true>
      <<<dim3(C / 128, M / 128), 256, 0, stream>>>(yb, wpb, out, bproj, M, C, C);
}